// Round 6
// baseline (447.162 us; speedup 1.0000x reference)
//
#include <hip/hip_runtime.h>

// Causal GQA attention: S=2048, H=32, KVH=8, D=128, fp32 in/out.
// R10: zero-LDS-staging: K/V pre-tiled in ws in fragment order, all MFMA
// operands via coalesced global_load_dwordx4 into registers; kvh==XCD swizzle.
// R10 post-mortem: per-iter 2980cyc with 57% issue-idle at 2 waves/SIMD;
// wall time == ip=0 block's 64 serial iterations. Latency-bound, TLP-starved.
// R11: INTRA-BLOCK SPLIT-K. 512-thread blocks (8 waves): waves 0-3 take the
// lower key half, waves 4-7 the upper half, same rows; partials combined
// through LDS (exact: this formulation has no running max, merge is add).
// Heavy/light pairing becomes two sequential phases -> every wave-group of
// every block runs exactly (32-ip)+(ip+1) = 33 iterations: critical path
// halves AND iteration-count tail vanishes. 2 blocks/CU x 8 waves = 4
// waves/SIMD (launch_bounds(512,4) => VGPR<=128). K(t+1) prefetch issued
// between QK and PV (covered by PV, shortens live ranges); V(t) loaded at
// body top (covered by QK). LDS only as 36KB combine scratch.

#define SEQ   2048
#define NH    32
#define NKV   8
#define HD    128
#define QLD   4096      // NH*HD
#define KLD   1024      // NKV*HD
#define KVB   32        // keys per tile

typedef __attribute__((ext_vector_type(8))) __bf16 bf16x8;
typedef __attribute__((ext_vector_type(4))) __bf16 bf16x4;
typedef __attribute__((ext_vector_type(2))) __bf16 bf16x2;
typedef __attribute__((ext_vector_type(4))) float  f32x4;
typedef __attribute__((ext_vector_type(4))) short  s16x4;
typedef __attribute__((ext_vector_type(2))) unsigned int u32x2;

static __device__ __forceinline__ unsigned int pack2(float lo, float hi) {
  bf16x2 t; t[0] = (__bf16)lo; t[1] = (__bf16)hi;
  return __builtin_bit_cast(unsigned int, t);
}

// PV matmul: D = A(V^T frag, 2 VGPR) * B(P frag = S^T C-layout regs) + C
static __device__ __forceinline__ f32x4 mfma16(bf16x4 a, u32x2 b, f32x4 c) {
#if __has_builtin(__builtin_amdgcn_mfma_f32_16x16x16bf16_1k)
  return __builtin_amdgcn_mfma_f32_16x16x16bf16_1k(
      __builtin_bit_cast(s16x4, a), __builtin_bit_cast(s16x4, b), c, 0, 0, 0);
#else
  asm volatile("v_mfma_f32_16x16x16_bf16 %0, %1, %2, %0"
               : "+v"(c) : "v"(a), "v"(b));
  return c;
#endif
}

// ---- pre-pass: build fragment-ordered bf16 tiles of K and V^T in ws ----
// KT tile (kvh,t): 8KB, slot = g*256 + c*64 + quad*16 + l15, 8 bf16/slot
//   = K[key = t*32 + g*16 + l15][dim = c*32 + quad*8 .. +8]
// VT tile (kvh,t): 8KB, slot = nt*64 + quad*16 + l15, 8 bf16/slot
//   = { V[key = t*32 + quad*4 .. +4][dim = nt*16 + l15],        (kt=0 half)
//       V[key = t*32 + 16 + quad*4 .. +4][dim] }                (kt=1 half)
__global__ void prep_tiles(const float* __restrict__ k, __bf16* __restrict__ kt,
                           const float* __restrict__ v, __bf16* __restrict__ vtt) {
  __shared__ __bf16 TT[HD][34];   // [dim][key32 + pad] (V half only)
  const int bx  = blockIdx.x;
  const int tid = threadIdx.x;
  const int kl  = tid >> 3;       // key-in-tile 0..31
  const int dc  = tid & 7;        // dim chunk of 16: dims dc*16..+16
  if (bx < 512) {                 // ---- K tiles ----
    const int kvh = bx >> 6, t = bx & 63;
    const float* src = k + (size_t)(t * 32 + kl) * KLD + kvh * HD + dc * 16;
    __bf16* dst = kt + (size_t)(kvh * 64 + t) * 4096;
    const int g = kl >> 4, l15 = kl & 15;
#pragma unroll
    for (int h = 0; h < 2; ++h) {
      const int d0 = dc * 16 + h * 8;
      const int c = d0 >> 5, quad = (d0 >> 3) & 3;
      float4 a0 = *(const float4*)(src + h * 8);
      float4 a1 = *(const float4*)(src + h * 8 + 4);
      bf16x8 f;
      f[0] = (__bf16)a0.x; f[1] = (__bf16)a0.y; f[2] = (__bf16)a0.z; f[3] = (__bf16)a0.w;
      f[4] = (__bf16)a1.x; f[5] = (__bf16)a1.y; f[6] = (__bf16)a1.z; f[7] = (__bf16)a1.w;
      const int slot = g * 256 + c * 64 + quad * 16 + l15;
      *(bf16x8*)(dst + slot * 8) = f;
    }
  } else {                        // ---- V tiles (transpose via LDS) ----
    const int b = bx - 512, kvh = b >> 6, t = b & 63;
    const float* src = v + (size_t)(t * 32 + kl) * KLD + kvh * HD + dc * 16;
#pragma unroll
    for (int jj = 0; jj < 4; ++jj) {
      float4 x = *(const float4*)(src + jj * 4);
      const int d = dc * 16 + jj * 4;
      TT[d + 0][kl] = (__bf16)x.x; TT[d + 1][kl] = (__bf16)x.y;
      TT[d + 2][kl] = (__bf16)x.z; TT[d + 3][kl] = (__bf16)x.w;
    }
    __syncthreads();
    __bf16* dst = vtt + (size_t)(kvh * 64 + t) * 4096;
#pragma unroll
    for (int ss = 0; ss < 2; ++ss) {
      const int s   = tid + ss * 256;
      const int nt  = s >> 6, quad = (s >> 4) & 3, l15 = s & 15;
      const int dim = nt * 16 + l15;
      bf16x8 f;
#pragma unroll
      for (int e = 0; e < 4; ++e) {
        f[e]     = TT[dim][quad * 4 + e];
        f[4 + e] = TT[dim][16 + quad * 4 + e];
      }
      *(bf16x8*)(dst + s * 8) = f;
    }
  }
}

// ---- main kernel: split-K within the block, LDS combine ----
__global__ __launch_bounds__(512, 4)
void fa_kernel(const float* __restrict__ q, const __bf16* __restrict__ kt,
               const __bf16* __restrict__ vtt, float* __restrict__ out) {
  __shared__ float CAcc[4][2048];   // [row-wave][nt*256 + lane*4]  (32 KB)
  __shared__ float CLp[4][256];     // [row-wave][lane*4]           (4 KB)

  // Flat-grid decode: kvh = bid&7 (== XCD on round-robin dispatch).
  const int bid  = blockIdx.x;
  const int kvh  = bid & 7;
  const int slot = bid >> 3;
  const int head = kvh * 4 + (slot & 3);
  const int ip   = slot >> 2;           // light tile = ip, heavy = 31-ip
  const int tid  = threadIdx.x;
  const int w    = tid >> 6;
  const int wg   = w >> 2;              // key-half group (0=lower,1=upper)
  const int wl   = w & 3;               // row-wave within group
  const int lane = tid & 63;
  const int l15  = lane & 15;
  const int quad = lane >> 4;

  constexpr float QS = 0.08838834764831845f * 1.4426950408889634f; // scale*log2e

  const __bf16* KT0 = kt  + (size_t)(kvh * 64) * 4096;
  const __bf16* VT0 = vtt + (size_t)(kvh * 64) * 4096;
  const int loff = lane * 8;   // elems

  auto phase = [&](int rowtile, int t0, int nkt) {
    const int rowbase = rowtile * 64 + wl * 16;

    // Q fragments (B-operand of S^T = K*Q^T): B[k=quad*8+j][n=l15]
    bf16x8 qf[4];
    {
      const float* qp = q + (size_t)(rowbase + l15) * QLD + head * HD + quad * 8;
#pragma unroll
      for (int c = 0; c < 4; ++c) {
        float4 a0 = *(const float4*)(qp + c * 32);
        float4 a1 = *(const float4*)(qp + c * 32 + 4);
        bf16x8 f;
        f[0] = (__bf16)(a0.x * QS); f[1] = (__bf16)(a0.y * QS);
        f[2] = (__bf16)(a0.z * QS); f[3] = (__bf16)(a0.w * QS);
        f[4] = (__bf16)(a1.x * QS); f[5] = (__bf16)(a1.y * QS);
        f[6] = (__bf16)(a1.z * QS); f[7] = (__bf16)(a1.w * QS);
        qf[c] = f;
      }
    }

    f32x4 acc[8];
    f32x4 lp = (f32x4){0.f, 0.f, 0.f, 0.f};
#pragma unroll
    for (int nt = 0; nt < 8; ++nt) acc[nt] = (f32x4){0.f, 0.f, 0.f, 0.f};

    bf16x8 kk0[2][4], kk1[2][4];
#pragma unroll
    for (int g = 0; g < 2; ++g)
#pragma unroll
      for (int c = 0; c < 4; ++c)
        kk0[g][c] = *(const bf16x8*)(KT0 + (size_t)t0 * 4096 + g * 2048 + c * 512 + loff);

    auto body = [&](int tt, bf16x8 (&kc)[2][4], bf16x8 (&kn)[2][4]) {
      const int t = t0 + tt;
      // V(t): consumed in PV below, latency covered by QK
      bf16x8 vv[8];
      const __bf16* vtile = VT0 + (size_t)t * 4096;
#pragma unroll
      for (int nt = 0; nt < 8; ++nt)
        vv[nt] = *(const bf16x8*)(vtile + nt * 512 + loff);

      // ---- S^T = K*Q^T (C-layout: key = quad*4+e, row = l15), exp2 ----
      u32x2 pknew[2];
#pragma unroll
      for (int g = 0; g < 2; ++g) {
        f32x4 s = (f32x4){0.f, 0.f, 0.f, 0.f};
        __builtin_amdgcn_s_setprio(1);
#pragma unroll
        for (int c = 0; c < 4; ++c)
          s = __builtin_amdgcn_mfma_f32_16x16x32_bf16(kc[g][c], qf[c], s, 0, 0, 0);
        __builtin_amdgcn_s_setprio(0);
        if (t * KVB + KVB - 1 > rowbase) {   // causal mask (wave-uniform)
          const int key0  = t * KVB + g * 16 + quad * 4;
          const int myrow = rowbase + l15;
#pragma unroll
          for (int e = 0; e < 4; ++e)
            if (key0 + e > myrow) s[e] = -1e30f;
        }
        f32x4 p;
#pragma unroll
        for (int e = 0; e < 4; ++e) p[e] = __builtin_amdgcn_exp2f(s[e]);
        lp += p;
        u32x2 pkk;
        pkk.x = pack2(p[0], p[1]);
        pkk.y = pack2(p[2], p[3]);
        pknew[g] = pkk;
      }

      // K(t+1) prefetch: issued after QK (kc now dead), covered by PV
      if (tt + 1 < nkt) {
        const __bf16* ktile = KT0 + (size_t)(t + 1) * 4096;
#pragma unroll
        for (int g = 0; g < 2; ++g)
#pragma unroll
          for (int c = 0; c < 4; ++c)
            kn[g][c] = *(const bf16x8*)(ktile + g * 2048 + c * 512 + loff);
      }

      // ---- O^T += V^T * P  (vv[nt] lo-half = kt0 frag, hi-half = kt1) ----
#pragma unroll
      for (int kt2 = 0; kt2 < 2; ++kt2) {
        __builtin_amdgcn_s_setprio(1);
#pragma unroll
        for (int nt = 0; nt < 8; ++nt) {
          bf16x4 vf;
#pragma unroll
          for (int e = 0; e < 4; ++e) vf[e] = vv[nt][kt2 * 4 + e];
          acc[nt] = mfma16(vf, pknew[kt2], acc[nt]);
        }
        __builtin_amdgcn_s_setprio(0);
      }
      __builtin_amdgcn_s_barrier();   // raw rendezvous: L1 alignment only
    };

    int tt = 0;
    for (; tt + 2 <= nkt; tt += 2) {
      body(tt,     kk0, kk1);
      body(tt + 1, kk1, kk0);
    }
    if (tt < nkt) body(tt, kk0, kk1);   // odd tail (no prefetch inside)

    // ---- combine the two key-halves via LDS, normalize, store ----
    if (wg == 1) {
#pragma unroll
      for (int nt = 0; nt < 8; ++nt)
        *(f32x4*)&CAcc[wl][nt * 256 + lane * 4] = acc[nt];
      *(f32x4*)&CLp[wl][lane * 4] = lp;
    }
    __syncthreads();
    if (wg == 0) {
      f32x4 plp = *(const f32x4*)&CLp[wl][lane * 4];
      lp += plp;
      float ls = lp[0] + lp[1] + lp[2] + lp[3];
      ls += __shfl_xor(ls, 16);
      ls += __shfl_xor(ls, 32);
      const float inv = 1.0f / ls;
      float* op = out + (size_t)(rowbase + l15) * QLD + head * HD + quad * 4;
#pragma unroll
      for (int nt = 0; nt < 8; ++nt) {
        f32x4 pa = *(const f32x4*)&CAcc[wl][nt * 256 + lane * 4];
        f32x4 r = acc[nt] + pa;
        float4 wv = {r[0] * inv, r[1] * inv, r[2] * inv, r[3] * inv};
        *(float4*)(op + nt * 16) = wv;
      }
    }
    __syncthreads();   // protect combine LDS for the next phase
  };

  // Heavy row-tile (31-ip): 2*(32-ip) key tiles, split 32-ip per group.
  const int nH = 32 - ip;
  phase(31 - ip, wg * nH, nH);
  // Light row-tile (ip): 2*(ip+1) key tiles, split ip+1 per group.
  const int nL = ip + 1;
  phase(ip, wg * nL, nL);
  // Per wave-group total: (32-ip)+(ip+1) = 33 iterations, uniform for all
  // 512 blocks -> no tail; critical path halved vs R10.
}

extern "C" void kernel_launch(void* const* d_in, const int* in_sizes, int n_in,
                              void* d_out, int out_size, void* d_ws, size_t ws_size,
                              hipStream_t stream) {
  const float* q = (const float*)d_in[0];
  const float* k = (const float*)d_in[1];
  const float* v = (const float*)d_in[2];
  float* o = (float*)d_out;
  __bf16* ktb = (__bf16*)d_ws;                          // 4 MB: K tiles
  __bf16* vtb = (__bf16*)d_ws + (size_t)SEQ * KLD;      // 4 MB: V^T tiles
  prep_tiles<<<1024, 256, 0, stream>>>(k, ktb, v, vtb);
  fa_kernel<<<512, 512, 0, stream>>>(q, ktb, vtb, o);
}

// Round 7
// 168.000 us; speedup vs baseline: 2.6617x; 2.6617x over previous
//
#include <hip/hip_runtime.h>

// Causal GQA attention: S=2048, H=32, KVH=8, D=128, fp32 in/out.
// R10: zero-LDS-staging: K/V pre-tiled in ws in fragment order, all MFMA
// operands via coalesced global_load_dwordx4 into registers; kvh==XCD swizzle.
// R11: intra-block split-K (8 waves: wg0=lower keys, wg1=upper keys, LDS
// combine); work-uniform 33 iters/block. Occupancy 43% proven mid-kernel, BUT
// kk double-buffer + vv + acc ~160 live regs vs the (512,4) 128-reg cap ->
// allocator spilled to scratch (WRITE 1.06GB, VGPR=64, 375us).
// R12: R11 minus register pressure. At 4 waves/SIMD, TLP replaces ILP:
// NO cross-tile K double-buffer (-32 regs), K(t) loaded at body top, V(t)
// after QK; single-buffered everything. Peak live ~105 < 128 -> no spill.
// Split-K, LDS combine, uniform iteration count, kvh==XCD decode, raw
// per-body s_barrier all kept from R11.

#define SEQ   2048
#define NH    32
#define NKV   8
#define HD    128
#define QLD   4096      // NH*HD
#define KLD   1024      // NKV*HD
#define KVB   32        // keys per tile

typedef __attribute__((ext_vector_type(8))) __bf16 bf16x8;
typedef __attribute__((ext_vector_type(4))) __bf16 bf16x4;
typedef __attribute__((ext_vector_type(2))) __bf16 bf16x2;
typedef __attribute__((ext_vector_type(4))) float  f32x4;
typedef __attribute__((ext_vector_type(4))) short  s16x4;
typedef __attribute__((ext_vector_type(2))) unsigned int u32x2;

static __device__ __forceinline__ unsigned int pack2(float lo, float hi) {
  bf16x2 t; t[0] = (__bf16)lo; t[1] = (__bf16)hi;
  return __builtin_bit_cast(unsigned int, t);
}

// PV matmul: D = A(V^T frag, 2 VGPR) * B(P frag = S^T C-layout regs) + C
static __device__ __forceinline__ f32x4 mfma16(bf16x4 a, u32x2 b, f32x4 c) {
#if __has_builtin(__builtin_amdgcn_mfma_f32_16x16x16bf16_1k)
  return __builtin_amdgcn_mfma_f32_16x16x16bf16_1k(
      __builtin_bit_cast(s16x4, a), __builtin_bit_cast(s16x4, b), c, 0, 0, 0);
#else
  asm volatile("v_mfma_f32_16x16x16_bf16 %0, %1, %2, %0"
               : "+v"(c) : "v"(a), "v"(b));
  return c;
#endif
}

// ---- pre-pass: build fragment-ordered bf16 tiles of K and V^T in ws ----
// KT tile (kvh,t): 8KB, slot = g*256 + c*64 + quad*16 + l15, 8 bf16/slot
//   = K[key = t*32 + g*16 + l15][dim = c*32 + quad*8 .. +8]
// VT tile (kvh,t): 8KB, slot = nt*64 + quad*16 + l15, 8 bf16/slot
//   = { V[key = t*32 + quad*4 .. +4][dim = nt*16 + l15],        (kt=0 half)
//       V[key = t*32 + 16 + quad*4 .. +4][dim] }                (kt=1 half)
__global__ void prep_tiles(const float* __restrict__ k, __bf16* __restrict__ kt,
                           const float* __restrict__ v, __bf16* __restrict__ vtt) {
  __shared__ __bf16 TT[HD][34];   // [dim][key32 + pad] (V half only)
  const int bx  = blockIdx.x;
  const int tid = threadIdx.x;
  const int kl  = tid >> 3;       // key-in-tile 0..31
  const int dc  = tid & 7;        // dim chunk of 16: dims dc*16..+16
  if (bx < 512) {                 // ---- K tiles ----
    const int kvh = bx >> 6, t = bx & 63;
    const float* src = k + (size_t)(t * 32 + kl) * KLD + kvh * HD + dc * 16;
    __bf16* dst = kt + (size_t)(kvh * 64 + t) * 4096;
    const int g = kl >> 4, l15 = kl & 15;
#pragma unroll
    for (int h = 0; h < 2; ++h) {
      const int d0 = dc * 16 + h * 8;
      const int c = d0 >> 5, quad = (d0 >> 3) & 3;
      float4 a0 = *(const float4*)(src + h * 8);
      float4 a1 = *(const float4*)(src + h * 8 + 4);
      bf16x8 f;
      f[0] = (__bf16)a0.x; f[1] = (__bf16)a0.y; f[2] = (__bf16)a0.z; f[3] = (__bf16)a0.w;
      f[4] = (__bf16)a1.x; f[5] = (__bf16)a1.y; f[6] = (__bf16)a1.z; f[7] = (__bf16)a1.w;
      const int slot = g * 256 + c * 64 + quad * 16 + l15;
      *(bf16x8*)(dst + slot * 8) = f;
    }
  } else {                        // ---- V tiles (transpose via LDS) ----
    const int b = bx - 512, kvh = b >> 6, t = b & 63;
    const float* src = v + (size_t)(t * 32 + kl) * KLD + kvh * HD + dc * 16;
#pragma unroll
    for (int jj = 0; jj < 4; ++jj) {
      float4 x = *(const float4*)(src + jj * 4);
      const int d = dc * 16 + jj * 4;
      TT[d + 0][kl] = (__bf16)x.x; TT[d + 1][kl] = (__bf16)x.y;
      TT[d + 2][kl] = (__bf16)x.z; TT[d + 3][kl] = (__bf16)x.w;
    }
    __syncthreads();
    __bf16* dst = vtt + (size_t)(kvh * 64 + t) * 4096;
#pragma unroll
    for (int ss = 0; ss < 2; ++ss) {
      const int s   = tid + ss * 256;
      const int nt  = s >> 6, quad = (s >> 4) & 3, l15 = s & 15;
      const int dim = nt * 16 + l15;
      bf16x8 f;
#pragma unroll
      for (int e = 0; e < 4; ++e) {
        f[e]     = TT[dim][quad * 4 + e];
        f[4 + e] = TT[dim][16 + quad * 4 + e];
      }
      *(bf16x8*)(dst + s * 8) = f;
    }
  }
}

// ---- main kernel: split-K within the block, LDS combine ----
__global__ __launch_bounds__(512, 4)
void fa_kernel(const float* __restrict__ q, const __bf16* __restrict__ kt,
               const __bf16* __restrict__ vtt, float* __restrict__ out) {
  __shared__ float CAcc[4][2048];   // [row-wave][nt*256 + lane*4]  (32 KB)
  __shared__ float CLp[4][256];     // [row-wave][lane*4]           (4 KB)

  // Flat-grid decode: kvh = bid&7 (== XCD on round-robin dispatch).
  const int bid  = blockIdx.x;
  const int kvh  = bid & 7;
  const int slot = bid >> 3;
  const int head = kvh * 4 + (slot & 3);
  const int ip   = slot >> 2;           // light tile = ip, heavy = 31-ip
  const int tid  = threadIdx.x;
  const int w    = tid >> 6;
  const int wg   = w >> 2;              // key-half group (0=lower,1=upper)
  const int wl   = w & 3;               // row-wave within group
  const int lane = tid & 63;
  const int l15  = lane & 15;
  const int quad = lane >> 4;

  constexpr float QS = 0.08838834764831845f * 1.4426950408889634f; // scale*log2e

  const __bf16* KT0 = kt  + (size_t)(kvh * 64) * 4096;
  const __bf16* VT0 = vtt + (size_t)(kvh * 64) * 4096;
  const int loff = lane * 8;   // elems

  auto phase = [&](int rowtile, int t0, int nkt) {
    const int rowbase = rowtile * 64 + wl * 16;

    // Q fragments (B-operand of S^T = K*Q^T): B[k=quad*8+j][n=l15]
    bf16x8 qf[4];
    {
      const float* qp = q + (size_t)(rowbase + l15) * QLD + head * HD + quad * 8;
#pragma unroll
      for (int c = 0; c < 4; ++c) {
        float4 a0 = *(const float4*)(qp + c * 32);
        float4 a1 = *(const float4*)(qp + c * 32 + 4);
        bf16x8 f;
        f[0] = (__bf16)(a0.x * QS); f[1] = (__bf16)(a0.y * QS);
        f[2] = (__bf16)(a0.z * QS); f[3] = (__bf16)(a0.w * QS);
        f[4] = (__bf16)(a1.x * QS); f[5] = (__bf16)(a1.y * QS);
        f[6] = (__bf16)(a1.z * QS); f[7] = (__bf16)(a1.w * QS);
        qf[c] = f;
      }
    }

    f32x4 acc[8];
    f32x4 lp = (f32x4){0.f, 0.f, 0.f, 0.f};
#pragma unroll
    for (int nt = 0; nt < 8; ++nt) acc[nt] = (f32x4){0.f, 0.f, 0.f, 0.f};

    for (int tt = 0; tt < nkt; ++tt) {
      const int t = t0 + tt;

      // K(t): single-buffered; latency hidden by the other 3 waves/SIMD (TLP)
      bf16x8 kk[2][4];
      {
        const __bf16* ktile = KT0 + (size_t)t * 4096;
#pragma unroll
        for (int g = 0; g < 2; ++g)
#pragma unroll
          for (int c = 0; c < 4; ++c)
            kk[g][c] = *(const bf16x8*)(ktile + g * 2048 + c * 512 + loff);
      }

      // ---- S^T = K*Q^T (C-layout: key = quad*4+e, row = l15), exp2 ----
      u32x2 pknew[2];
#pragma unroll
      for (int g = 0; g < 2; ++g) {
        f32x4 s = (f32x4){0.f, 0.f, 0.f, 0.f};
        __builtin_amdgcn_s_setprio(1);
#pragma unroll
        for (int c = 0; c < 4; ++c)
          s = __builtin_amdgcn_mfma_f32_16x16x32_bf16(kk[g][c], qf[c], s, 0, 0, 0);
        __builtin_amdgcn_s_setprio(0);
        if (t * KVB + KVB - 1 > rowbase) {   // causal mask (wave-uniform)
          const int key0  = t * KVB + g * 16 + quad * 4;
          const int myrow = rowbase + l15;
#pragma unroll
          for (int e = 0; e < 4; ++e)
            if (key0 + e > myrow) s[e] = -1e30f;
        }
        f32x4 p;
#pragma unroll
        for (int e = 0; e < 4; ++e) p[e] = __builtin_amdgcn_exp2f(s[e]);
        lp += p;
        u32x2 pkk;
        pkk.x = pack2(p[0], p[1]);
        pkk.y = pack2(p[2], p[3]);
        pknew[g] = pkk;
      }

      // V(t): loaded after QK (kk dead) -> peak-live stays under the 128 cap
      bf16x8 vv[8];
      {
        const __bf16* vtile = VT0 + (size_t)t * 4096;
#pragma unroll
        for (int nt = 0; nt < 8; ++nt)
          vv[nt] = *(const bf16x8*)(vtile + nt * 512 + loff);
      }

      // ---- O^T += V^T * P  (vv[nt] lo-half = kt0 frag, hi-half = kt1) ----
#pragma unroll
      for (int kt2 = 0; kt2 < 2; ++kt2) {
        __builtin_amdgcn_s_setprio(1);
#pragma unroll
        for (int nt = 0; nt < 8; ++nt) {
          bf16x4 vf;
#pragma unroll
          for (int e = 0; e < 4; ++e) vf[e] = vv[nt][kt2 * 4 + e];
          acc[nt] = mfma16(vf, pknew[kt2], acc[nt]);
        }
        __builtin_amdgcn_s_setprio(0);
      }
      __builtin_amdgcn_s_barrier();   // raw rendezvous: L1 alignment only
    }

    // ---- combine the two key-halves via LDS, normalize, store ----
    if (wg == 1) {
#pragma unroll
      for (int nt = 0; nt < 8; ++nt)
        *(f32x4*)&CAcc[wl][nt * 256 + lane * 4] = acc[nt];
      *(f32x4*)&CLp[wl][lane * 4] = lp;
    }
    __syncthreads();
    if (wg == 0) {
      f32x4 plp = *(const f32x4*)&CLp[wl][lane * 4];
      lp += plp;
      float ls = lp[0] + lp[1] + lp[2] + lp[3];
      ls += __shfl_xor(ls, 16);
      ls += __shfl_xor(ls, 32);
      const float inv = 1.0f / ls;
      float* op = out + (size_t)(rowbase + l15) * QLD + head * HD + quad * 4;
#pragma unroll
      for (int nt = 0; nt < 8; ++nt) {
        f32x4 pa = *(const f32x4*)&CAcc[wl][nt * 256 + lane * 4];
        f32x4 r = acc[nt] + pa;
        float4 wv = {r[0] * inv, r[1] * inv, r[2] * inv, r[3] * inv};
        *(float4*)(op + nt * 16) = wv;
      }
    }
    __syncthreads();   // protect combine LDS for the next phase
  };

  // Heavy row-tile (31-ip): 2*(32-ip) key tiles, split 32-ip per group.
  const int nH = 32 - ip;
  phase(31 - ip, wg * nH, nH);
  // Light row-tile (ip): 2*(ip+1) key tiles, split ip+1 per group.
  const int nL = ip + 1;
  phase(ip, wg * nL, nL);
  // Per wave-group total: (32-ip)+(ip+1) = 33 iterations, uniform for all
  // 512 blocks -> no tail; critical path halved vs R10.
}

extern "C" void kernel_launch(void* const* d_in, const int* in_sizes, int n_in,
                              void* d_out, int out_size, void* d_ws, size_t ws_size,
                              hipStream_t stream) {
  const float* q = (const float*)d_in[0];
  const float* k = (const float*)d_in[1];
  const float* v = (const float*)d_in[2];
  float* o = (float*)d_out;
  __bf16* ktb = (__bf16*)d_ws;                          // 4 MB: K tiles
  __bf16* vtb = (__bf16*)d_ws + (size_t)SEQ * KLD;      // 4 MB: V^T tiles
  prep_tiles<<<1024, 256, 0, stream>>>(k, ktb, v, vtb);
  fa_kernel<<<512, 512, 0, stream>>>(q, ktb, vtb, o);
}

// Round 8
// 136.318 us; speedup vs baseline: 3.2803x; 1.2324x over previous
//
#include <hip/hip_runtime.h>

// Causal GQA attention: S=2048, H=32, KVH=8, D=128, fp32 in/out.
// R10: zero-LDS-staging: K/V pre-tiled in ws in fragment order, all MFMA
// operands via coalesced global_load_dwordx4 into registers; kvh==XCD swizzle.
// R11: intra-block split-K; spilled (160 live vs 128 cap).
// R12: spill fixed (single-buffer, V-after-QK). 93.8us. Post-mortem traffic
// accounting: EVERY WAVE privately streams the full 16KB K+V tile through
// TCP (~64B/cyc/CU). R12: 16 waves/CU x 16KB = 256KB/iter ~ 4000cyc demand,
// 6000 measured; total 2.2GB at ~23TB/s == the wall. 16 rows/wave = 16
// FLOP/byte is the real constraint, not occupancy (35% didn't help).
// R13: 32 ROWS PER WAVE (two 16-row subs) -> 2x FLOP/byte, traffic 1.1GB.
// 512 x 256-thr blocks: 4 waves = 2 row-waves (32 rows each, covering the
// 64-row tile) x 2 key-halves. R12's split-K + uniform heavy->light phases
// kept (33 iters/wave, timeline-uniform). 2 waves/SIMD -> reg cap 256:
// peak live ~200 (acc64+qf32+kk32+vv32+misc), V loaded BEFORE QK. Per-body
// barrier deleted (key-halves read disjoint tiles). 36KB LDS combine.

#define SEQ   2048
#define NH    32
#define NKV   8
#define HD    128
#define QLD   4096      // NH*HD
#define KLD   1024      // NKV*HD
#define KVB   32        // keys per tile

typedef __attribute__((ext_vector_type(8))) __bf16 bf16x8;
typedef __attribute__((ext_vector_type(4))) __bf16 bf16x4;
typedef __attribute__((ext_vector_type(2))) __bf16 bf16x2;
typedef __attribute__((ext_vector_type(4))) float  f32x4;
typedef __attribute__((ext_vector_type(4))) short  s16x4;
typedef __attribute__((ext_vector_type(2))) unsigned int u32x2;

static __device__ __forceinline__ unsigned int pack2(float lo, float hi) {
  bf16x2 t; t[0] = (__bf16)lo; t[1] = (__bf16)hi;
  return __builtin_bit_cast(unsigned int, t);
}

// PV matmul: D = A(V^T frag, 2 VGPR) * B(P frag = S^T C-layout regs) + C
static __device__ __forceinline__ f32x4 mfma16(bf16x4 a, u32x2 b, f32x4 c) {
#if __has_builtin(__builtin_amdgcn_mfma_f32_16x16x16bf16_1k)
  return __builtin_amdgcn_mfma_f32_16x16x16bf16_1k(
      __builtin_bit_cast(s16x4, a), __builtin_bit_cast(s16x4, b), c, 0, 0, 0);
#else
  asm volatile("v_mfma_f32_16x16x16_bf16 %0, %1, %2, %0"
               : "+v"(c) : "v"(a), "v"(b));
  return c;
#endif
}

// ---- pre-pass: build fragment-ordered bf16 tiles of K and V^T in ws ----
// KT tile (kvh,t): 8KB, slot = g*256 + c*64 + quad*16 + l15, 8 bf16/slot
//   = K[key = t*32 + g*16 + l15][dim = c*32 + quad*8 .. +8]
// VT tile (kvh,t): 8KB, slot = nt*64 + quad*16 + l15, 8 bf16/slot
//   = { V[key = t*32 + quad*4 .. +4][dim = nt*16 + l15],        (kt=0 half)
//       V[key = t*32 + 16 + quad*4 .. +4][dim] }                (kt=1 half)
__global__ void prep_tiles(const float* __restrict__ k, __bf16* __restrict__ kt,
                           const float* __restrict__ v, __bf16* __restrict__ vtt) {
  __shared__ __bf16 TT[HD][34];   // [dim][key32 + pad] (V half only)
  const int bx  = blockIdx.x;
  const int tid = threadIdx.x;
  const int kl  = tid >> 3;       // key-in-tile 0..31
  const int dc  = tid & 7;        // dim chunk of 16: dims dc*16..+16
  if (bx < 512) {                 // ---- K tiles ----
    const int kvh = bx >> 6, t = bx & 63;
    const float* src = k + (size_t)(t * 32 + kl) * KLD + kvh * HD + dc * 16;
    __bf16* dst = kt + (size_t)(kvh * 64 + t) * 4096;
    const int g = kl >> 4, l15 = kl & 15;
#pragma unroll
    for (int h = 0; h < 2; ++h) {
      const int d0 = dc * 16 + h * 8;
      const int c = d0 >> 5, quad = (d0 >> 3) & 3;
      float4 a0 = *(const float4*)(src + h * 8);
      float4 a1 = *(const float4*)(src + h * 8 + 4);
      bf16x8 f;
      f[0] = (__bf16)a0.x; f[1] = (__bf16)a0.y; f[2] = (__bf16)a0.z; f[3] = (__bf16)a0.w;
      f[4] = (__bf16)a1.x; f[5] = (__bf16)a1.y; f[6] = (__bf16)a1.z; f[7] = (__bf16)a1.w;
      const int slot = g * 256 + c * 64 + quad * 16 + l15;
      *(bf16x8*)(dst + slot * 8) = f;
    }
  } else {                        // ---- V tiles (transpose via LDS) ----
    const int b = bx - 512, kvh = b >> 6, t = b & 63;
    const float* src = v + (size_t)(t * 32 + kl) * KLD + kvh * HD + dc * 16;
#pragma unroll
    for (int jj = 0; jj < 4; ++jj) {
      float4 x = *(const float4*)(src + jj * 4);
      const int d = dc * 16 + jj * 4;
      TT[d + 0][kl] = (__bf16)x.x; TT[d + 1][kl] = (__bf16)x.y;
      TT[d + 2][kl] = (__bf16)x.z; TT[d + 3][kl] = (__bf16)x.w;
    }
    __syncthreads();
    __bf16* dst = vtt + (size_t)(kvh * 64 + t) * 4096;
#pragma unroll
    for (int ss = 0; ss < 2; ++ss) {
      const int s   = tid + ss * 256;
      const int nt  = s >> 6, quad = (s >> 4) & 3, l15 = s & 15;
      const int dim = nt * 16 + l15;
      bf16x8 f;
#pragma unroll
      for (int e = 0; e < 4; ++e) {
        f[e]     = TT[dim][quad * 4 + e];
        f[4 + e] = TT[dim][16 + quad * 4 + e];
      }
      *(bf16x8*)(dst + s * 8) = f;
    }
  }
}

// ---- main kernel: 32 rows/wave, split-K within the block, LDS combine ----
__global__ __launch_bounds__(256, 2)
void fa_kernel(const float* __restrict__ q, const __bf16* __restrict__ kt,
               const __bf16* __restrict__ vtt, float* __restrict__ out) {
  __shared__ float CAcc[2][2][8][256];  // [row-wave][sub][nt][lane*4]  32 KB
  __shared__ float CLp[2][2][256];      // [row-wave][sub][lane*4]       4 KB

  // Flat-grid decode: kvh = bid&7 (== XCD on round-robin dispatch).
  const int bid  = blockIdx.x;
  const int kvh  = bid & 7;
  const int slot = bid >> 3;
  const int head = kvh * 4 + (slot & 3);
  const int ip   = slot >> 2;           // light tile = ip, heavy = 31-ip
  const int tid  = threadIdx.x;
  const int w    = tid >> 6;
  const int rw   = w & 1;               // row-wave: rows rw*32 .. rw*32+31
  const int wg   = w >> 1;              // key-half group (0=lower,1=upper)
  const int lane = tid & 63;
  const int l15  = lane & 15;
  const int quad = lane >> 4;

  constexpr float QS = 0.08838834764831845f * 1.4426950408889634f; // scale*log2e

  const __bf16* KT0 = kt  + (size_t)(kvh * 64) * 4096;
  const __bf16* VT0 = vtt + (size_t)(kvh * 64) * 4096;
  const int loff = lane * 8;   // elems

  auto phase = [&](int rowtile, int t0, int nkt) {
    const int rowbase = rowtile * 64 + rw * 32;   // sub s rows: rowbase+s*16..

    // Q fragments per sub (B-operand of S^T = K*Q^T): B[k=quad*8+j][n=l15]
    bf16x8 qf[2][4];
#pragma unroll
    for (int sub = 0; sub < 2; ++sub) {
      const float* qp = q + (size_t)(rowbase + sub * 16 + l15) * QLD + head * HD + quad * 8;
#pragma unroll
      for (int c = 0; c < 4; ++c) {
        float4 a0 = *(const float4*)(qp + c * 32);
        float4 a1 = *(const float4*)(qp + c * 32 + 4);
        bf16x8 f;
        f[0] = (__bf16)(a0.x * QS); f[1] = (__bf16)(a0.y * QS);
        f[2] = (__bf16)(a0.z * QS); f[3] = (__bf16)(a0.w * QS);
        f[4] = (__bf16)(a1.x * QS); f[5] = (__bf16)(a1.y * QS);
        f[6] = (__bf16)(a1.z * QS); f[7] = (__bf16)(a1.w * QS);
        qf[sub][c] = f;
      }
    }

    f32x4 acc[2][8];
    f32x4 lp[2];
#pragma unroll
    for (int sub = 0; sub < 2; ++sub) {
      lp[sub] = (f32x4){0.f, 0.f, 0.f, 0.f};
#pragma unroll
      for (int nt = 0; nt < 8; ++nt) acc[sub][nt] = (f32x4){0.f, 0.f, 0.f, 0.f};
    }

    for (int tt = 0; tt < nkt; ++tt) {
      const int t = t0 + tt;

      // K(t) then V(t): V is independent of QK, lands during QK+softmax.
      bf16x8 kk[2][4];
      {
        const __bf16* ktile = KT0 + (size_t)t * 4096;
#pragma unroll
        for (int g = 0; g < 2; ++g)
#pragma unroll
          for (int c = 0; c < 4; ++c)
            kk[g][c] = *(const bf16x8*)(ktile + g * 2048 + c * 512 + loff);
      }
      bf16x8 vv[8];
      {
        const __bf16* vtile = VT0 + (size_t)t * 4096;
#pragma unroll
        for (int nt = 0; nt < 8; ++nt)
          vv[nt] = *(const bf16x8*)(vtile + nt * 512 + loff);
      }

      // ---- S^T = K*Q^T (C-layout: key = quad*4+e, row = l15), exp2 ----
      u32x2 pk[2][2];   // [sub][g]
#pragma unroll
      for (int g = 0; g < 2; ++g) {
#pragma unroll
        for (int sub = 0; sub < 2; ++sub) {
          f32x4 s = (f32x4){0.f, 0.f, 0.f, 0.f};
          __builtin_amdgcn_s_setprio(1);
#pragma unroll
          for (int c = 0; c < 4; ++c)
            s = __builtin_amdgcn_mfma_f32_16x16x32_bf16(kk[g][c], qf[sub][c], s, 0, 0, 0);
          __builtin_amdgcn_s_setprio(0);
          const int rb = rowbase + sub * 16;
          if (t * KVB + KVB - 1 > rb) {      // causal mask (wave-uniform)
            const int key0  = t * KVB + g * 16 + quad * 4;
            const int myrow = rb + l15;
#pragma unroll
            for (int e = 0; e < 4; ++e)
              if (key0 + e > myrow) s[e] = -1e30f;
          }
          f32x4 p;
#pragma unroll
          for (int e = 0; e < 4; ++e) p[e] = __builtin_amdgcn_exp2f(s[e]);
          lp[sub] += p;
          u32x2 pkk;
          pkk.x = pack2(p[0], p[1]);
          pkk.y = pack2(p[2], p[3]);
          pk[sub][g] = pkk;
        }
      }

      // ---- O^T += V^T * P  (vv[nt] lo-half = kt0 frag, hi-half = kt1) ----
#pragma unroll
      for (int kt2 = 0; kt2 < 2; ++kt2) {
        __builtin_amdgcn_s_setprio(1);
#pragma unroll
        for (int nt = 0; nt < 8; ++nt) {
          bf16x4 vf;
#pragma unroll
          for (int e = 0; e < 4; ++e) vf[e] = vv[nt][kt2 * 4 + e];
          acc[0][nt] = mfma16(vf, pk[0][kt2], acc[0][nt]);
          acc[1][nt] = mfma16(vf, pk[1][kt2], acc[1][nt]);
        }
        __builtin_amdgcn_s_setprio(0);
      }
      // no per-body barrier: key-halves read disjoint tiles, nothing to align
    }

    // ---- combine the two key-halves via LDS, normalize, store ----
    __syncthreads();
    if (wg == 1) {
#pragma unroll
      for (int sub = 0; sub < 2; ++sub) {
#pragma unroll
        for (int nt = 0; nt < 8; ++nt)
          *(f32x4*)&CAcc[rw][sub][nt][lane * 4] = acc[sub][nt];
        *(f32x4*)&CLp[rw][sub][lane * 4] = lp[sub];
      }
    }
    __syncthreads();
    if (wg == 0) {
#pragma unroll
      for (int sub = 0; sub < 2; ++sub) {
        f32x4 plp = *(const f32x4*)&CLp[rw][sub][lane * 4];
        f32x4 l = lp[sub] + plp;
        float ls = l[0] + l[1] + l[2] + l[3];
        ls += __shfl_xor(ls, 16);
        ls += __shfl_xor(ls, 32);
        const float inv = 1.0f / ls;
        float* op = out + (size_t)(rowbase + sub * 16 + l15) * QLD + head * HD + quad * 4;
#pragma unroll
        for (int nt = 0; nt < 8; ++nt) {
          f32x4 pa = *(const f32x4*)&CAcc[rw][sub][nt][lane * 4];
          f32x4 r = acc[sub][nt] + pa;
          float4 wv = {r[0] * inv, r[1] * inv, r[2] * inv, r[3] * inv};
          *(float4*)(op + nt * 16) = wv;
        }
      }
    }
    __syncthreads();   // protect combine LDS for the next phase
  };

  // Heavy row-tile (31-ip): 64-2ip key tiles, split 32-ip per key-half.
  const int nH = 32 - ip;
  phase(31 - ip, wg * nH, nH);
  // Light row-tile (ip): 2ip+2 key tiles, split ip+1 per key-half.
  const int nL = ip + 1;
  phase(ip, wg * nL, nL);
  // Per wave: (32-ip)+(ip+1) = 33 iterations, uniform across all 512 blocks.
}

extern "C" void kernel_launch(void* const* d_in, const int* in_sizes, int n_in,
                              void* d_out, int out_size, void* d_ws, size_t ws_size,
                              hipStream_t stream) {
  const float* q = (const float*)d_in[0];
  const float* k = (const float*)d_in[1];
  const float* v = (const float*)d_in[2];
  float* o = (float*)d_out;
  __bf16* ktb = (__bf16*)d_ws;                          // 4 MB: K tiles
  __bf16* vtb = (__bf16*)d_ws + (size_t)SEQ * KLD;      // 4 MB: V^T tiles
  prep_tiles<<<1024, 256, 0, stream>>>(k, ktb, v, vtb);
  fa_kernel<<<512, 256, 0, stream>>>(q, ktb, vtb, o);
}